// Round 4
// baseline (59.564 us; speedup 1.0000x reference)
//
#include <hip/hip_runtime.h>
#include <hip/hip_bf16.h>
#include <math.h>

// Problem constants (B=4, T=2048, D=1024, H=64), fp32 in/out.
#define Bb   4
#define Tlen 2048
#define Dd   1024
#define Hh   64
#define NROWS 8192      // B*T
#define NQ   32         // q-tiles of 64 rows per batch

typedef short bf16x8 __attribute__((ext_vector_type(8)));
typedef float f32x4  __attribute__((ext_vector_type(4)));

__device__ __forceinline__ unsigned short f2b(float f) {
    unsigned u = __float_as_uint(f);
    unsigned r = u + 0x7FFFu + ((u >> 16) & 1u);   // RNE
    return (unsigned short)(r >> 16);
}
__device__ __forceinline__ unsigned pk2(float a, float b) {   // 2xf32 -> packed bf16x2 (RNE)
    __hip_bfloat162 h = __float22bfloat162_rn(make_float2(a, b));
    return *reinterpret_cast<unsigned*>(&h);
}

// ---------------- Kernel 0: W -> MFMA B-fragment layout ----------------
// wfrag[((f*12 + nb)*64 + lane)*8 + j] = W[k][n],  f = t*2+ks (k-step of 32),
// nb = n>>4, lane = 16*g + (n&15), k = (f>>1)*64 + (f&1)*32 + g*8 + j.
// n = wsel*64 + h over the q|k|v concat (192 cols).
__global__ __launch_bounds__(256) void wtrans_kernel(
    const float* __restrict__ Wq, const float* __restrict__ Wk,
    const float* __restrict__ Wv, unsigned short* __restrict__ wfrag)
{
    const int s = blockIdx.x * 256 + threadIdx.x;    // 0..24575
    const int f   = s / 768;
    const int rem = s % 768;
    const int nb  = rem >> 6;
    const int lane = rem & 63;
    const int g = lane >> 4, qr = lane & 15;
    const int n = nb * 16 + qr;
    const int wsel = n >> 6, h = n & 63;
    const float* W = (wsel == 0) ? Wq : (wsel == 1) ? Wk : Wv;
    const int k0 = (f >> 1) * 64 + (f & 1) * 32 + g * 8;
    unsigned short tmp[8];
    #pragma unroll
    for (int j = 0; j < 8; ++j) tmp[j] = f2b(W[(size_t)(k0 + j) * Hh + h]);
    *(bf16x8*)(wfrag + (size_t)s * 8) = *(const bf16x8*)tmp;
}

// ---------------- Kernel 1: fused QKV projection, LDS-free ----------------
// 512 blocks x 128 threads. block = 32 rows x 96 cols (colhalf).
// wave wv: rows rb+16*wv..+15. No LDS, no barriers: A from x (fp32->bf16 in
// regs), B from wfrag (coalesced b128, L2-resident). Compiler pipelines.
__global__ __launch_bounds__(128) void proj_kernel(
    const float* __restrict__ x, const unsigned short* __restrict__ wfrag,
    unsigned short* __restrict__ qw, unsigned short* __restrict__ kw,
    unsigned short* __restrict__ vw)
{
    const int bx = blockIdx.x;
    const int rb = (bx >> 1) * 32;
    const int ch = bx & 1;
    const int wv = threadIdx.x >> 6;
    const int lane = threadIdx.x & 63;
    const int qr = lane & 15, g = lane >> 4;

    const float* xp = x + (size_t)(rb + wv * 16 + qr) * Dd + g * 8;
    const unsigned short* wp = wfrag + ((size_t)(ch * 6) * 64 + lane) * 8;

    f32x4 acc[6] = {};

    #pragma unroll
    for (int t = 0; t < 16; ++t) {
        #pragma unroll
        for (int ks = 0; ks < 2; ++ks) {
            const float4 v0 = *(const float4*)(xp + t * 64 + ks * 32);
            const float4 v1 = *(const float4*)(xp + t * 64 + ks * 32 + 4);
            union { unsigned u[4]; bf16x8 v; } a;
            a.u[0] = pk2(v0.x, v0.y);
            a.u[1] = pk2(v0.z, v0.w);
            a.u[2] = pk2(v1.x, v1.y);
            a.u[3] = pk2(v1.z, v1.w);
            const int f = t * 2 + ks;
            #pragma unroll
            for (int nf = 0; nf < 6; ++nf) {
                const bf16x8 b = *(const bf16x8*)(wp + (size_t)(f * 12 + nf) * 512);
                acc[nf] = __builtin_amdgcn_mfma_f32_16x16x32_bf16(a.v, b, acc[nf], 0, 0, 0);
            }
        }
    }

    #pragma unroll
    for (int nf = 0; nf < 6; ++nf) {
        const int n = ch * 96 + nf * 16 + qr;
        const int wsel = n >> 6, h = n & 63;
        unsigned short* out = (wsel == 0) ? qw : (wsel == 1) ? kw : vw;
        #pragma unroll
        for (int r = 0; r < 4; ++r)
            out[(size_t)(rb + wv * 16 + 4 * g + r) * Hh + h] = f2b(acc[nf][r]);
    }
}

// ---------------- Kernel 2: flash attention partials (MFMA bf16) ----------------
// grid (NQ, nc, B). Block: 4 waves; wave w owns q-rows qt*64+16w .. +15.
// Swapped QK^T: mfma(A=K, B=Q) -> lane holds S[q=lane&15][j=4*(lane>>4)+r].
#define XSTR 72
#define VSTR 40   // V^T LDS row stride (80 B)
__global__ __launch_bounds__(256) void attn_kernel(
    const unsigned short* __restrict__ qw, const unsigned short* __restrict__ kw,
    const unsigned short* __restrict__ vw,
    float* __restrict__ part_O, float* __restrict__ part_ml, int nc)
{
    __shared__ unsigned short ks_s[32 * XSTR];
    __shared__ unsigned short vt_s[64 * VSTR];

    const int qt = (NQ - 1) - blockIdx.x;   // big q-tiles dispatched first
    const int ci = blockIdx.y;
    const int b  = blockIdx.z;
    const int tid = threadIdx.x;
    const int wv = tid >> 6, lane = tid & 63;
    const int qr = lane & 15, g = lane >> 4;

    const int ntk = 2 * qt + 2;                    // causal key tiles of 32
    const int tpc = (ntk + nc - 1) / nc;
    const int t0  = ci * tpc;
    const int t1  = (ntk < t0 + tpc) ? ntk : (t0 + tpc);

    const size_t base = (size_t)b * Tlen * Hh;
    const int qrow = qt * 64 + wv * 16 + qr;       // this lane's q row (within b)

    // Q fragments (k-halves 0..31, 32..63) straight from global (bf16)
    const bf16x8 qf0 = *(const bf16x8*)(qw + base + (size_t)qrow * Hh + 8 * g);
    const bf16x8 qf1 = *(const bf16x8*)(qw + base + (size_t)qrow * Hh + 32 + 8 * g);

    f32x4 o0 = {}, o1 = {}, o2 = {}, o3 = {};
    float m = -INFINITY, l = 0.f;

    for (int kt = t0; kt < t1; ++kt) {
        const int j0 = kt * 32;
        __syncthreads();
        {   // stage K tile [32][64] (row-XOR swizzle) + V^T tile [64][32] (col-group swizzle)
            const int row = tid >> 3, cg = tid & 7;
            const bf16x8 k8 = *(const bf16x8*)(kw + base + (size_t)(j0 + row) * Hh + cg * 8);
            *(bf16x8*)(&ks_s[row * XSTR + ((cg ^ (row & 3)) << 3)]) = k8;
            const bf16x8 v8 = *(const bf16x8*)(vw + base + (size_t)(j0 + row) * Hh + cg * 8);
            #pragma unroll
            for (int u = 0; u < 8; ++u) {
                const int c = cg * 8 + u;
                const int jx = row ^ (((c >> 3) & 3) << 3);
                vt_s[c * VSTR + jx] = ((const unsigned short*)&v8)[u];
            }
        }
        __syncthreads();

        // S^T = K . Q^T  (two j-frags, K contraction over H=64 in 2 steps)
        f32x4 a0 = {}, a1 = {};
        {
            const int sw = (g ^ (qr & 3)) << 3;
            bf16x8 kf;
            kf = *(const bf16x8*)(&ks_s[qr * XSTR + sw]);
            a0 = __builtin_amdgcn_mfma_f32_16x16x32_bf16(kf, qf0, a0, 0, 0, 0);
            kf = *(const bf16x8*)(&ks_s[qr * XSTR + 32 + sw]);
            a0 = __builtin_amdgcn_mfma_f32_16x16x32_bf16(kf, qf1, a0, 0, 0, 0);
            kf = *(const bf16x8*)(&ks_s[(16 + qr) * XSTR + sw]);
            a1 = __builtin_amdgcn_mfma_f32_16x16x32_bf16(kf, qf0, a1, 0, 0, 0);
            kf = *(const bf16x8*)(&ks_s[(16 + qr) * XSTR + 32 + sw]);
            a1 = __builtin_amdgcn_mfma_f32_16x16x32_bf16(kf, qf1, a1, 0, 0, 0);
        }

        // masked scores, online softmax (lane owns row q=qr; j = jf*16 + 4g + r)
        float p[8];
        float tm = -INFINITY;
        #pragma unroll
        for (int jf = 0; jf < 2; ++jf) {
            #pragma unroll
            for (int r = 0; r < 4; ++r) {
                const int jg = j0 + jf * 16 + 4 * g + r;
                float s = ((jf == 0) ? a0[r] : a1[r]) * 0.125f;
                s = (jg > qrow) ? -INFINITY : s;
                p[jf * 4 + r] = s;
                tm = fmaxf(tm, s);
            }
        }
        tm = fmaxf(tm, __shfl_xor(tm, 16));
        tm = fmaxf(tm, __shfl_xor(tm, 32));
        const float mnew  = fmaxf(m, tm);
        const float alpha = (m == -INFINITY) ? 0.f : __expf(m - mnew);
        float psum = 0.f;
        #pragma unroll
        for (int i = 0; i < 8; ++i) {
            const float pv = (p[i] == -INFINITY) ? 0.f : __expf(p[i] - mnew);
            p[i] = pv; psum += pv;
        }
        psum += __shfl_xor(psum, 16);
        psum += __shfl_xor(psum, 32);
        l = l * alpha + psum;
        m = mnew;

        // rescale O (rows q = 4g+r need alpha of that q-row)
        const float ar0 = __shfl(alpha, 4 * g + 0);
        const float ar1 = __shfl(alpha, 4 * g + 1);
        const float ar2 = __shfl(alpha, 4 * g + 2);
        const float ar3 = __shfl(alpha, 4 * g + 3);
        o0[0] *= ar0; o0[1] *= ar1; o0[2] *= ar2; o0[3] *= ar3;
        o1[0] *= ar0; o1[1] *= ar1; o1[2] *= ar2; o1[3] *= ar3;
        o2[0] *= ar0; o2[1] *= ar1; o2[2] *= ar2; o2[3] *= ar3;
        o3[0] *= ar0; o3[1] *= ar1; o3[2] *= ar2; o3[3] *= ar3;

        // repack P (S^T layout) -> PV A-fragment (8 shuffles, in-register)
        unsigned pw[4];
        pw[0] = f2b(p[0]) | ((unsigned)f2b(p[1]) << 16);   // jf0: j=4g+0,1
        pw[1] = f2b(p[2]) | ((unsigned)f2b(p[3]) << 16);   // jf0: j=4g+2,3
        pw[2] = f2b(p[4]) | ((unsigned)f2b(p[5]) << 16);   // jf1: j=16+4g+0,1
        pw[3] = f2b(p[6]) | ((unsigned)f2b(p[7]) << 16);   // jf1: j=16+4g+2,3
        union PU { unsigned u[4]; bf16x8 v; } pu;
        #pragma unroll
        for (int w = 0; w < 4; ++w) {
            const int gp  = 2 * g + (w >> 1);          // source group of j = 8g+2w
            const int src = 16 * (gp & 3) + qr;
            const unsigned t0s = __shfl(pw[0 + (w & 1)], src);
            const unsigned t1s = __shfl(pw[2 + (w & 1)], src);
            pu.u[w] = (gp & 4) ? t1s : t0s;
        }
        const bf16x8 pa = pu.v;

        // O += P . V  (B-frag from swizzled V^T)
        {
            int cb = qr;
            bf16x8 vf = *(const bf16x8*)(&vt_s[cb * VSTR + 8 * (g ^ ((cb >> 3) & 3))]);
            o0 = __builtin_amdgcn_mfma_f32_16x16x32_bf16(pa, vf, o0, 0, 0, 0);
            cb = 16 + qr;
            vf = *(const bf16x8*)(&vt_s[cb * VSTR + 8 * (g ^ ((cb >> 3) & 3))]);
            o1 = __builtin_amdgcn_mfma_f32_16x16x32_bf16(pa, vf, o1, 0, 0, 0);
            cb = 32 + qr;
            vf = *(const bf16x8*)(&vt_s[cb * VSTR + 8 * (g ^ ((cb >> 3) & 3))]);
            o2 = __builtin_amdgcn_mfma_f32_16x16x32_bf16(pa, vf, o2, 0, 0, 0);
            cb = 48 + qr;
            vf = *(const bf16x8*)(&vt_s[cb * VSTR + 8 * (g ^ ((cb >> 3) & 3))]);
            o3 = __builtin_amdgcn_mfma_f32_16x16x32_bf16(pa, vf, o3, 0, 0, 0);
        }
    }

    // write partials (unnormalized O', m, l)
    const int blin = (b * NQ + qt) * nc + ci;
    float* po = part_O + (size_t)blin * 4096;
    #pragma unroll
    for (int nf = 0; nf < 4; ++nf) {
        const f32x4 ov = (nf == 0) ? o0 : (nf == 1) ? o1 : (nf == 2) ? o2 : o3;
        #pragma unroll
        for (int r = 0; r < 4; ++r)
            po[(size_t)(wv * 16 + 4 * g + r) * 64 + nf * 16 + qr] = ov[r];
    }
    if (g == 0) {
        part_ml[(size_t)blin * 128 + wv * 16 + qr]      = m;
        part_ml[(size_t)blin * 128 + 64 + wv * 16 + qr] = l;
    }
}

// ---------------- Kernel 3: merge partials ----------------
__global__ __launch_bounds__(256) void merge_kernel(
    const float* __restrict__ part_O, const float* __restrict__ part_ml,
    float* __restrict__ out, int nc)
{
    const int idx = blockIdx.x * 256 + threadIdx.x;   // 0 .. 524287
    const int row = idx >> 6;       // 0..8191
    const int c   = idx & 63;
    const int b   = row >> 11;
    const int t   = row & 2047;
    const int qt  = t >> 6;
    const int qq  = t & 63;
    const int bl0 = (b * NQ + qt) * nc;

    float M = -INFINITY;
    for (int i = 0; i < nc; ++i) {
        const float lvi = part_ml[(size_t)(bl0 + i) * 128 + 64 + qq];
        if (lvi > 0.f) M = fmaxf(M, part_ml[(size_t)(bl0 + i) * 128 + qq]);
    }
    float num = 0.f, den = 0.f;
    for (int i = 0; i < nc; ++i) {
        const float lvi = part_ml[(size_t)(bl0 + i) * 128 + 64 + qq];
        if (lvi > 0.f) {
            const float wgt = __expf(part_ml[(size_t)(bl0 + i) * 128 + qq] - M);
            num += wgt * part_O[(size_t)(bl0 + i) * 4096 + (size_t)qq * 64 + c];
            den += wgt * lvi;
        }
    }
    out[(size_t)row * 64 + c] = num / den;
}

extern "C" void kernel_launch(void* const* d_in, const int* in_sizes, int n_in,
                              void* d_out, int out_size, void* d_ws, size_t ws_size,
                              hipStream_t stream) {
    const float* x  = (const float*)d_in[0];
    const float* Wq = (const float*)d_in[1];
    const float* Wk = (const float*)d_in[2];
    const float* Wv = (const float*)d_in[3];
    float* outp = (float*)d_out;

    // choose flash-split width by available workspace
    const size_t fixed_b = (size_t)192 * 1024 * 2 + 3ull * NROWS * Hh * 2;
    int nc = 8;
    if (fixed_b + (size_t)(Bb * NQ * 8) * (4096 + 128) * 4 > ws_size) nc = 4;

    unsigned short* wfrag = (unsigned short*)d_ws;      // 192*1024 bf16
    unsigned short* qw = wfrag + 192 * 1024;            // 8192*64 each
    unsigned short* kw = qw + NROWS * Hh;
    unsigned short* vw = kw + NROWS * Hh;
    float* part_O  = (float*)(vw + NROWS * Hh);         // (Bb*NQ*nc) * 4096
    float* part_ml = part_O + (size_t)(Bb * NQ * nc) * 4096;

    wtrans_kernel<<<dim3(96), 256, 0, stream>>>(Wq, Wk, Wv, wfrag);
    proj_kernel<<<dim3(512), 128, 0, stream>>>(x, wfrag, qw, kw, vw);
    attn_kernel<<<dim3(NQ, nc, Bb), 256, 0, stream>>>(qw, kw, vw, part_O, part_ml, nc);
    merge_kernel<<<dim3((NROWS * Hh) / 256), 256, 0, stream>>>(part_O, part_ml, outp, nc);
}

// Round 5
// 49.340 us; speedup vs baseline: 1.2072x; 1.2072x over previous
//
#include <hip/hip_runtime.h>
#include <hip/hip_bf16.h>
#include <math.h>

// Problem constants (B=4, T=2048, D=1024, H=64), fp32 in/out.
#define Bb   4
#define Tlen 2048
#define Dd   1024
#define Hh   64
#define NROWS 8192      // B*T
#define NQ   32         // q-tiles of 64 rows per batch
#define NC   4          // flash-decoding split

typedef short bf16x8 __attribute__((ext_vector_type(8)));
typedef float f32x4  __attribute__((ext_vector_type(4)));

__device__ __forceinline__ unsigned short f2b(float f) {
    unsigned u = __float_as_uint(f);
    unsigned r = u + 0x7FFFu + ((u >> 16) & 1u);   // RNE
    return (unsigned short)(r >> 16);
}
__device__ __forceinline__ unsigned pk2(float a, float b) {   // 2xf32 -> packed bf16x2 (RNE)
    __hip_bfloat162 h = __float22bfloat162_rn(make_float2(a, b));
    return *reinterpret_cast<unsigned*>(&h);
}

// ---------------- Kernel 0: W -> MFMA B-fragment layout ----------------
// wfrag[((f*12 + nb)*64 + lane)*8 + j] = W[k][n],  f = t*2+ks (k-step of 32),
// nb = n>>4, lane = 16*g + (n&15), k = (f>>1)*64 + (f&1)*32 + g*8 + j.
// n = wsel*64 + h over the q|k|v concat (192 cols).
__global__ __launch_bounds__(256) void wtrans_kernel(
    const float* __restrict__ Wq, const float* __restrict__ Wk,
    const float* __restrict__ Wv, unsigned short* __restrict__ wfrag)
{
    const int s = blockIdx.x * 256 + threadIdx.x;    // 0..24575
    const int f   = s / 768;
    const int rem = s % 768;
    const int nb  = rem >> 6;
    const int lane = rem & 63;
    const int g = lane >> 4, qr = lane & 15;
    const int n = nb * 16 + qr;
    const int wsel = n >> 6, h = n & 63;
    const float* W = (wsel == 0) ? Wq : (wsel == 1) ? Wk : Wv;
    const int k0 = (f >> 1) * 64 + (f & 1) * 32 + g * 8;
    unsigned short tmp[8];
    #pragma unroll
    for (int j = 0; j < 8; ++j) tmp[j] = f2b(W[(size_t)(k0 + j) * Hh + h]);
    *(bf16x8*)(wfrag + (size_t)s * 8) = *(const bf16x8*)tmp;
}

// ---------------- Kernel 1: fused QKV projection (hybrid) ----------------
// 256 blocks x 256 threads; block = 32 rows x 192 cols. Wave wv = N-slice
// wv*48..+47 (3 frags) x 2 M-frags. x staged coalesced -> LDS (bf16, XOR
// swizzle, double-buffered); W read as B-frags straight from L2 (coalesced,
// no barrier dependency -> compiler pipelines across the unrolled K-loop).
__global__ __launch_bounds__(256) void proj_kernel(
    const float* __restrict__ x, const unsigned short* __restrict__ wfrag,
    unsigned short* __restrict__ qw, unsigned short* __restrict__ kw,
    unsigned short* __restrict__ vw)
{
    __shared__ unsigned short xs[2][32 * 64];

    const int rb   = blockIdx.x * 32;
    const int tid  = threadIdx.x;
    const int wv   = tid >> 6;
    const int lane = tid & 63;
    const int qr   = lane & 15;
    const int g    = lane >> 4;

    // staging coords: 8 lanes per row -> 256 B contiguous per row
    const int xr = tid >> 3, xc8 = tid & 7;
    const float* xg0 = x + (size_t)(rb + xr) * Dd + xc8 * 8;

    // per-wave W base: nb = wv*3 + nf  ->  addr = wp + (f*12 + nf)*512
    const unsigned short* wp = wfrag + ((size_t)(wv * 3) * 64 + lane) * 8;

    f32x4 acc[6] = {};   // [mf][nf]

    float4 px0 = *(const float4*)(xg0 + 0);
    float4 px1 = *(const float4*)(xg0 + 4);

    #pragma unroll
    for (int t = 0; t < 16; ++t) {
        const int cur = t & 1;
        // ---- write staged x (step t) into buf[cur] ----
        {
            union { unsigned u[4]; bf16x8 v; } p8;
            p8.u[0] = pk2(px0.x, px0.y);
            p8.u[1] = pk2(px0.z, px0.w);
            p8.u[2] = pk2(px1.x, px1.y);
            p8.u[3] = pk2(px1.z, px1.w);
            *(bf16x8*)(&xs[cur][xr * 64 + ((xc8 ^ (xr & 7)) << 3)]) = p8.v;
        }
        __syncthreads();

        // ---- issue next-step x loads (hide under MFMA) ----
        if (t < 15) {
            px0 = *(const float4*)(xg0 + (t + 1) * 64 + 0);
            px1 = *(const float4*)(xg0 + (t + 1) * 64 + 4);
        }

        // ---- compute on buf[cur] ----
        #pragma unroll
        for (int ks = 0; ks < 2; ++ks) {
            const int f = t * 2 + ks;
            bf16x8 b0 = *(const bf16x8*)(wp + (size_t)(f * 12 + 0) * 512);
            bf16x8 b1 = *(const bf16x8*)(wp + (size_t)(f * 12 + 1) * 512);
            bf16x8 b2 = *(const bf16x8*)(wp + (size_t)(f * 12 + 2) * 512);
            #pragma unroll
            for (int mf = 0; mf < 2; ++mf) {
                const int arow = mf * 16 + qr;
                const bf16x8 a = *(const bf16x8*)(
                    &xs[cur][arow * 64 + (((ks * 4 + g) ^ (arow & 7)) << 3)]);
                acc[mf * 3 + 0] = __builtin_amdgcn_mfma_f32_16x16x32_bf16(a, b0, acc[mf * 3 + 0], 0, 0, 0);
                acc[mf * 3 + 1] = __builtin_amdgcn_mfma_f32_16x16x32_bf16(a, b1, acc[mf * 3 + 1], 0, 0, 0);
                acc[mf * 3 + 2] = __builtin_amdgcn_mfma_f32_16x16x32_bf16(a, b2, acc[mf * 3 + 2], 0, 0, 0);
            }
        }
        __syncthreads();
    }

    // ---- epilogue: D[m = mf*16 + 4g + r][n = wv*48 + nf*16 + qr] ----
    #pragma unroll
    for (int mf = 0; mf < 2; ++mf) {
        #pragma unroll
        for (int nf = 0; nf < 3; ++nf) {
            const int n = wv * 48 + nf * 16 + qr;
            const int wsel = n >> 6, h = n & 63;
            unsigned short* out = (wsel == 0) ? qw : (wsel == 1) ? kw : vw;
            const f32x4 ov = acc[mf * 3 + nf];
            #pragma unroll
            for (int r = 0; r < 4; ++r)
                out[(size_t)(rb + mf * 16 + 4 * g + r) * Hh + h] = f2b(ov[r]);
        }
    }
}

// ---------------- Kernel 2: flash attention partials (MFMA bf16) ----------------
// grid (NQ, NC, B). Block: 4 waves; wave w owns q-rows qt*64+16w .. +15.
// Swapped QK^T: mfma(A=K, B=Q) -> lane holds S[q=lane&15][j=4*(lane>>4)+r].
#define XSTR 72
#define VSTR 40   // V^T LDS row stride (80 B)
__global__ __launch_bounds__(256) void attn_kernel(
    const unsigned short* __restrict__ qw, const unsigned short* __restrict__ kw,
    const unsigned short* __restrict__ vw,
    float* __restrict__ part_O, float* __restrict__ part_ml)
{
    __shared__ unsigned short ks_s[32 * XSTR];
    __shared__ unsigned short vt_s[64 * VSTR];

    const int qt = (NQ - 1) - blockIdx.x;   // big q-tiles dispatched first
    const int ci = blockIdx.y;
    const int b  = blockIdx.z;
    const int tid = threadIdx.x;
    const int wv = tid >> 6, lane = tid & 63;
    const int qr = lane & 15, g = lane >> 4;

    const int ntk = 2 * qt + 2;                    // causal key tiles of 32
    const int tpc = (ntk + NC - 1) / NC;
    const int t0  = ci * tpc;
    const int t1  = (ntk < t0 + tpc) ? ntk : (t0 + tpc);

    const size_t base = (size_t)b * Tlen * Hh;
    const int qrow = qt * 64 + wv * 16 + qr;       // this lane's q row (within b)

    // Q fragments (k-halves 0..31, 32..63) straight from global (bf16)
    const bf16x8 qf0 = *(const bf16x8*)(qw + base + (size_t)qrow * Hh + 8 * g);
    const bf16x8 qf1 = *(const bf16x8*)(qw + base + (size_t)qrow * Hh + 32 + 8 * g);

    f32x4 o0 = {}, o1 = {}, o2 = {}, o3 = {};
    float m = -INFINITY, l = 0.f;

    for (int kt = t0; kt < t1; ++kt) {
        const int j0 = kt * 32;
        __syncthreads();
        {   // stage K tile [32][64] (row-XOR swizzle) + V^T tile [64][32] (col-group swizzle)
            const int row = tid >> 3, cg = tid & 7;
            const bf16x8 k8 = *(const bf16x8*)(kw + base + (size_t)(j0 + row) * Hh + cg * 8);
            *(bf16x8*)(&ks_s[row * XSTR + ((cg ^ (row & 3)) << 3)]) = k8;
            const bf16x8 v8 = *(const bf16x8*)(vw + base + (size_t)(j0 + row) * Hh + cg * 8);
            #pragma unroll
            for (int u = 0; u < 8; ++u) {
                const int c = cg * 8 + u;
                const int jx = row ^ (((c >> 3) & 3) << 3);
                vt_s[c * VSTR + jx] = ((const unsigned short*)&v8)[u];
            }
        }
        __syncthreads();

        // S^T = K . Q^T  (two j-frags, K contraction over H=64 in 2 steps)
        f32x4 a0 = {}, a1 = {};
        {
            const int sw = (g ^ (qr & 3)) << 3;
            bf16x8 kf;
            kf = *(const bf16x8*)(&ks_s[qr * XSTR + sw]);
            a0 = __builtin_amdgcn_mfma_f32_16x16x32_bf16(kf, qf0, a0, 0, 0, 0);
            kf = *(const bf16x8*)(&ks_s[qr * XSTR + 32 + sw]);
            a0 = __builtin_amdgcn_mfma_f32_16x16x32_bf16(kf, qf1, a0, 0, 0, 0);
            kf = *(const bf16x8*)(&ks_s[(16 + qr) * XSTR + sw]);
            a1 = __builtin_amdgcn_mfma_f32_16x16x32_bf16(kf, qf0, a1, 0, 0, 0);
            kf = *(const bf16x8*)(&ks_s[(16 + qr) * XSTR + 32 + sw]);
            a1 = __builtin_amdgcn_mfma_f32_16x16x32_bf16(kf, qf1, a1, 0, 0, 0);
        }

        // masked scores, online softmax (lane owns row q=qr; j = jf*16 + 4g + r)
        float p[8];
        float tm = -INFINITY;
        #pragma unroll
        for (int jf = 0; jf < 2; ++jf) {
            #pragma unroll
            for (int r = 0; r < 4; ++r) {
                const int jg = j0 + jf * 16 + 4 * g + r;
                float s = ((jf == 0) ? a0[r] : a1[r]) * 0.125f;
                s = (jg > qrow) ? -INFINITY : s;
                p[jf * 4 + r] = s;
                tm = fmaxf(tm, s);
            }
        }
        tm = fmaxf(tm, __shfl_xor(tm, 16));
        tm = fmaxf(tm, __shfl_xor(tm, 32));
        const float mnew  = fmaxf(m, tm);
        const float alpha = (m == -INFINITY) ? 0.f : __expf(m - mnew);
        float psum = 0.f;
        #pragma unroll
        for (int i = 0; i < 8; ++i) {
            const float pv = (p[i] == -INFINITY) ? 0.f : __expf(p[i] - mnew);
            p[i] = pv; psum += pv;
        }
        psum += __shfl_xor(psum, 16);
        psum += __shfl_xor(psum, 32);
        l = l * alpha + psum;
        m = mnew;

        // rescale O (rows q = 4g+r need alpha of that q-row)
        const float ar0 = __shfl(alpha, 4 * g + 0);
        const float ar1 = __shfl(alpha, 4 * g + 1);
        const float ar2 = __shfl(alpha, 4 * g + 2);
        const float ar3 = __shfl(alpha, 4 * g + 3);
        o0[0] *= ar0; o0[1] *= ar1; o0[2] *= ar2; o0[3] *= ar3;
        o1[0] *= ar0; o1[1] *= ar1; o1[2] *= ar2; o1[3] *= ar3;
        o2[0] *= ar0; o2[1] *= ar1; o2[2] *= ar2; o2[3] *= ar3;
        o3[0] *= ar0; o3[1] *= ar1; o3[2] *= ar2; o3[3] *= ar3;

        // repack P (S^T layout) -> PV A-fragment (8 shuffles, in-register)
        unsigned pw[4];
        pw[0] = f2b(p[0]) | ((unsigned)f2b(p[1]) << 16);   // jf0: j=4g+0,1
        pw[1] = f2b(p[2]) | ((unsigned)f2b(p[3]) << 16);   // jf0: j=4g+2,3
        pw[2] = f2b(p[4]) | ((unsigned)f2b(p[5]) << 16);   // jf1: j=16+4g+0,1
        pw[3] = f2b(p[6]) | ((unsigned)f2b(p[7]) << 16);   // jf1: j=16+4g+2,3
        union PU { unsigned u[4]; bf16x8 v; } pu;
        #pragma unroll
        for (int w = 0; w < 4; ++w) {
            const int gp  = 2 * g + (w >> 1);          // source group of j = 8g+2w
            const int src = 16 * (gp & 3) + qr;
            const unsigned t0s = __shfl(pw[0 + (w & 1)], src);
            const unsigned t1s = __shfl(pw[2 + (w & 1)], src);
            pu.u[w] = (gp & 4) ? t1s : t0s;
        }
        const bf16x8 pa = pu.v;

        // O += P . V  (B-frag from swizzled V^T)
        {
            int cb = qr;
            bf16x8 vf = *(const bf16x8*)(&vt_s[cb * VSTR + 8 * (g ^ ((cb >> 3) & 3))]);
            o0 = __builtin_amdgcn_mfma_f32_16x16x32_bf16(pa, vf, o0, 0, 0, 0);
            cb = 16 + qr;
            vf = *(const bf16x8*)(&vt_s[cb * VSTR + 8 * (g ^ ((cb >> 3) & 3))]);
            o1 = __builtin_amdgcn_mfma_f32_16x16x32_bf16(pa, vf, o1, 0, 0, 0);
            cb = 32 + qr;
            vf = *(const bf16x8*)(&vt_s[cb * VSTR + 8 * (g ^ ((cb >> 3) & 3))]);
            o2 = __builtin_amdgcn_mfma_f32_16x16x32_bf16(pa, vf, o2, 0, 0, 0);
            cb = 48 + qr;
            vf = *(const bf16x8*)(&vt_s[cb * VSTR + 8 * (g ^ ((cb >> 3) & 3))]);
            o3 = __builtin_amdgcn_mfma_f32_16x16x32_bf16(pa, vf, o3, 0, 0, 0);
        }
    }

    // write partials (unnormalized O', m, l)
    const int blin = (b * NQ + qt) * NC + ci;
    float* po = part_O + (size_t)blin * 4096;
    #pragma unroll
    for (int nf = 0; nf < 4; ++nf) {
        const f32x4 ov = (nf == 0) ? o0 : (nf == 1) ? o1 : (nf == 2) ? o2 : o3;
        #pragma unroll
        for (int r = 0; r < 4; ++r)
            po[(size_t)(wv * 16 + 4 * g + r) * 64 + nf * 16 + qr] = ov[r];
    }
    if (g == 0) {
        part_ml[(size_t)blin * 128 + wv * 16 + qr]      = m;
        part_ml[(size_t)blin * 128 + 64 + wv * 16 + qr] = l;
    }
}

// ---------------- Kernel 3: merge partials ----------------
__global__ __launch_bounds__(256) void merge_kernel(
    const float* __restrict__ part_O, const float* __restrict__ part_ml,
    float* __restrict__ out)
{
    const int idx = blockIdx.x * 256 + threadIdx.x;   // 0 .. 524287
    const int row = idx >> 6;       // 0..8191
    const int c   = idx & 63;
    const int b   = row >> 11;
    const int t   = row & 2047;
    const int qt  = t >> 6;
    const int qq  = t & 63;
    const int bl0 = (b * NQ + qt) * NC;

    float M = -INFINITY;
    #pragma unroll
    for (int i = 0; i < NC; ++i) {
        const float lvi = part_ml[(size_t)(bl0 + i) * 128 + 64 + qq];
        if (lvi > 0.f) M = fmaxf(M, part_ml[(size_t)(bl0 + i) * 128 + qq]);
    }
    float num = 0.f, den = 0.f;
    #pragma unroll
    for (int i = 0; i < NC; ++i) {
        const float lvi = part_ml[(size_t)(bl0 + i) * 128 + 64 + qq];
        if (lvi > 0.f) {
            const float wgt = __expf(part_ml[(size_t)(bl0 + i) * 128 + qq] - M);
            num += wgt * part_O[(size_t)(bl0 + i) * 4096 + (size_t)qq * 64 + c];
            den += wgt * lvi;
        }
    }
    out[(size_t)row * 64 + c] = num / den;
}

extern "C" void kernel_launch(void* const* d_in, const int* in_sizes, int n_in,
                              void* d_out, int out_size, void* d_ws, size_t ws_size,
                              hipStream_t stream) {
    const float* x  = (const float*)d_in[0];
    const float* Wq = (const float*)d_in[1];
    const float* Wk = (const float*)d_in[2];
    const float* Wv = (const float*)d_in[3];
    float* outp = (float*)d_out;

    unsigned short* wfrag = (unsigned short*)d_ws;      // 192*1024 bf16
    unsigned short* qw = wfrag + 192 * 1024;            // 8192*64 each
    unsigned short* kw = qw + NROWS * Hh;
    unsigned short* vw = kw + NROWS * Hh;
    float* part_O  = (float*)(vw + NROWS * Hh);         // (Bb*NQ*NC) * 4096
    float* part_ml = part_O + (size_t)(Bb * NQ * NC) * 4096;

    wtrans_kernel<<<dim3(96), 256, 0, stream>>>(Wq, Wk, Wv, wfrag);
    proj_kernel<<<dim3(NROWS / 32), 256, 0, stream>>>(x, wfrag, qw, kw, vw);
    attn_kernel<<<dim3(NQ, NC, Bb), 256, 0, stream>>>(qw, kw, vw, part_O, part_ml);
    merge_kernel<<<dim3((NROWS * Hh) / 256), 256, 0, stream>>>(part_O, part_ml, outp);
}